// Round 7
// baseline (200.529 us; speedup 1.0000x reference)
//
#include <hip/hip_runtime.h>
#include <math.h>

#define TOKENS 16384
#define HIDDEN 2048
#define BM 256
#define BN 256
#define BK 64
#define NT (HIDDEN / BK)   // 32 K-tiles

typedef __attribute__((ext_vector_type(4))) float f32x4;
typedef __attribute__((ext_vector_type(16))) float f32x16;
typedef __attribute__((ext_vector_type(8))) short s16x8;

__device__ __forceinline__ unsigned short f2bf(float f) {
  unsigned int u = __float_as_uint(f);
  u += 0x7fffu + ((u >> 16) & 1u);   // round-to-nearest-even
  return (unsigned short)(u >> 16);
}

// tanh-approx GELU via raw v_exp_f32 + v_rcp_f32; |err vs erf-gelu| ~1e-3.
__device__ __forceinline__ float fast_gelu(float y) {
  float t = y * fmaf(y * y, 0.044715f, 1.0f);
  float e = __builtin_amdgcn_exp2f(-2.3022082f * t);
  return y * __builtin_amdgcn_rcpf(1.0f + e);
}

// ---------------- kernel 0: W fp32 -> bf16 ----------------
__global__ __launch_bounds__(256) void wconv_kernel(const float* __restrict__ W,
                                                    unsigned short* __restrict__ Wb) {
  const int n4 = (HIDDEN * HIDDEN) / 4;
  for (int i = blockIdx.x * 256 + threadIdx.x; i < n4; i += gridDim.x * 256) {
    float4 v = *(const float4*)(W + (size_t)i * 4);
    ushort4 o;
    o.x = f2bf(v.x); o.y = f2bf(v.y); o.z = f2bf(v.z); o.w = f2bf(v.w);
    *(ushort4*)(Wb + (size_t)i * 4) = o;
  }
}

// ---------------- kernel 1: LayerNorm fp32 -> bf16, one block per row ----------------
__global__ __launch_bounds__(256) void ln_kernel(const float* __restrict__ x,
                                                 const float* __restrict__ gamma,
                                                 const float* __restrict__ beta,
                                                 unsigned short* __restrict__ xn) {
  const int row = blockIdx.x;
  const int t = threadIdx.x;
  const int wave = t >> 6, lane = t & 63;
  const float* xr = x + (size_t)row * HIDDEN + t * 8;
  float4 v0 = *(const float4*)(xr);
  float4 v1 = *(const float4*)(xr + 4);
  float xv[8] = {v0.x, v0.y, v0.z, v0.w, v1.x, v1.y, v1.z, v1.w};

  float s = 0.f, ss = 0.f;
#pragma unroll
  for (int j = 0; j < 8; ++j) { s += xv[j]; ss = fmaf(xv[j], xv[j], ss); }

#pragma unroll
  for (int off = 32; off > 0; off >>= 1) {
    s += __shfl_xor(s, off, 64);
    ss += __shfl_xor(ss, off, 64);
  }
  __shared__ float rs[4], rss[4];
  if (lane == 0) { rs[wave] = s; rss[wave] = ss; }
  __syncthreads();
  s = rs[0] + rs[1] + rs[2] + rs[3];
  ss = rss[0] + rss[1] + rss[2] + rss[3];

  const float mean = s * (1.0f / HIDDEN);
  const float var = ss * (1.0f / HIDDEN) - mean * mean;
  const float rstd = rsqrtf(var + 1e-5f);

  float4 g0 = *(const float4*)(gamma + t * 8);
  float4 g1 = *(const float4*)(gamma + t * 8 + 4);
  float4 b0 = *(const float4*)(beta + t * 8);
  float4 b1 = *(const float4*)(beta + t * 8 + 4);
  float gv[8] = {g0.x, g0.y, g0.z, g0.w, g1.x, g1.y, g1.z, g1.w};
  float bv[8] = {b0.x, b0.y, b0.z, b0.w, b1.x, b1.y, b1.z, b1.w};

  union { unsigned short h[8]; uint4 q; } pk;
#pragma unroll
  for (int j = 0; j < 8; ++j)
    pk.h[j] = f2bf((xv[j] - mean) * rstd * gv[j] + bv[j]);
  *(uint4*)(xn + (size_t)row * HIDDEN + t * 8) = pk.q;
}

// ---------------- kernel 2: 256x256 4-phase bf16 GEMM (32x32x16 MFMA) + bias + GELU ---
// A[M,K] * B[N,K]^T. 512 threads = 8 waves (2M x 4N), per-wave output 128x64.
// Round-3 verified 4-phase snake schedule, fragments switched to mfma_f32_32x32x16_bf16
// (2382 TF ubench vs 2075 for 16x16x32; half the MFMA instruction count).
// Fragment geometry: A row=l&31, k=(l>>5)*8+j (slot = 2*ks + (l>>5));
// C/D col=lane&31, row=(reg&3)+8*(reg>>2)+4*(lane>>5)  [m74/m101-verified].
// ds_read counts per phase {12,4,8,4} and all vmcnt/lgkmcnt arithmetic unchanged.
// LDS 128 KiB: 2 buf x {A,B} x 2 half x 2 quarter x 8KB. XOR swizzle ((row&7)<<4) on
// gather source AND ds_read side. XCD pin: tn = wg&7 (B panel 1MB L2-resident/XCD).

#define GLOAD(gp, lp) __builtin_amdgcn_global_load_lds( \
    (const __attribute__((address_space(1))) unsigned int*)(gp), \
    (__attribute__((address_space(3))) unsigned int*)(lp), 16, 0, 0)

__global__ __launch_bounds__(512, 1) void gemm_kernel(const unsigned short* __restrict__ A,
                                                      const unsigned short* __restrict__ B,
                                                      const float* __restrict__ bias,
                                                      float* __restrict__ out) {
  __shared__ __attribute__((aligned(16))) char lds[131072];

  const int tid = threadIdx.x;
  const int lane = tid & 63;
  const int wave = tid >> 6;
  const int l31 = lane & 31, hi32 = lane >> 5;

  // XCD pin: hardware round-robins wgs to XCDs (XCD = wg%8); tn = wg&7 keeps each
  // XCD on ONE B column panel (1 MB, L2-resident). tm = wg>>3 streams A (L3-resident).
  const int wg = blockIdx.x;
  const int tm = wg >> 3, tn = wg & 7;   // 64 M-tiles x 8 N-tiles
  const int row0 = tm * BM, col0 = tn * BN;

  const int wmi = wave >> 2;        // wave M index (0..1)
  const int wni = wave & 3;         // wave N index (0..3)
  const int hB = wni >> 1, gB = wni & 1;

  // ---- staging geometry (per-lane gather, pre-swizzled source) ----
  const int rho = tid >> 3, sig = tid & 7;
  const int colgrp = ((sig ^ (rho & 7)) << 3);                 // k-element offset
  const unsigned short* Ap = A + (size_t)(row0 + rho) * HIDDEN + colgrp;
  const unsigned short* Bp = B + (size_t)(col0 + ((rho >> 5) << 6) + (rho & 31)) * HIDDEN + colgrp;
  const int ldsWaveOff = wave << 10;                            // 64 lanes * 16B

  // ---- ds_read per-lane constants: frag row + swizzled k-slot for ks=0..3 ----
  int aoff[4], boff[4];
#pragma unroll
  for (int ks = 0; ks < 4; ++ks) {
    const int sb = (((2 * ks + hi32) ^ (lane & 7)) << 4);   // swizzled 16B slot
    aoff[ks] = (l31 << 7) + sb;                             // A chunk-row = mi*32 + l31
    boff[ks] = (((gB << 5) + l31) << 7) + sb;               // B chunk-row = gB*32 + l31
  }

  auto stageA = [&](int tt, int bufd, int qm) {     // 2 calls: both halves of quarter qm
    const int tc = tt < NT ? tt : NT - 1;
    const unsigned short* g = Ap + (size_t)(qm << 6) * HIDDEN + tc * BK;
    GLOAD(g, lds + ((((bufd << 2) | qm) << 13)) + ldsWaveOff);
    GLOAD(g + (size_t)128 * HIDDEN, lds + ((((bufd << 2) | 2 | qm) << 13)) + ldsWaveOff);
  };
  auto stageB = [&](int tt, int bufd, int qn) {
    const int tc = tt < NT ? tt : NT - 1;
    const unsigned short* g = Bp + (size_t)(qn << 5) * HIDDEN + tc * BK;
    GLOAD(g, lds + 65536 + ((((bufd << 2) | qn) << 13)) + ldsWaveOff);
    GLOAD(g + (size_t)128 * HIDDEN, lds + 65536 + ((((bufd << 2) | 2 | qn) << 13)) + ldsWaveOff);
  };

  f32x16 acc[4][2] = {};     // [mi_global 0..3 = 32-row blocks][qn32 0..1 = 32-col blocks]
  s16x8 a[2][4], b[4];

  // ---- prologue: tile0 fully + tile1's first 2 quarters, steady-state age order ----
  stageA(0, 0, 0); stageB(0, 0, 1); stageA(0, 0, 1); stageB(0, 0, 0);
  stageA(1, 1, 0); stageB(1, 1, 1);
  asm volatile("s_waitcnt vmcnt(4)" ::: "memory");   // tile0's 8 calls landed
  __builtin_amdgcn_s_barrier();

  for (int t = 0; t < NT; ++t) {
    const int buf = t & 1;
    const char* Abase = lds + (((buf << 2) | (wmi << 1)) << 13);
    const char* Bbase = lds + 65536 + (((buf << 2) | (hB << 1)) << 13);

    // ===== p0: quadrant (qm=0, qn=0): 8 A reads + 4 B reads, 8 MFMA =====
#pragma unroll
    for (int mi = 0; mi < 2; ++mi)
#pragma unroll
      for (int ks = 0; ks < 4; ++ks)
        a[mi][ks] = *(const s16x8*)(Abase + mi * 4096 + aoff[ks]);
#pragma unroll
    for (int ks = 0; ks < 4; ++ks)
      b[ks] = *(const s16x8*)(Bbase + boff[ks]);
    stageA(t + 1, buf ^ 1, 1);
    asm volatile("s_waitcnt lgkmcnt(8)" ::: "memory");
    __builtin_amdgcn_s_barrier();
    asm volatile("s_waitcnt lgkmcnt(0)" ::: "memory");
    __builtin_amdgcn_s_setprio(1);
#pragma unroll
    for (int mi = 0; mi < 2; ++mi)
#pragma unroll
      for (int ks = 0; ks < 4; ++ks)
        acc[mi][0] = __builtin_amdgcn_mfma_f32_32x32x16_bf16(a[mi][ks], b[ks], acc[mi][0], 0, 0, 0);
    __builtin_amdgcn_s_setprio(0);
    __builtin_amdgcn_s_barrier();

    // ===== p1: quadrant (qm=0, qn=1) — reuse a; 4 B reads =====
#pragma unroll
    for (int ks = 0; ks < 4; ++ks)
      b[ks] = *(const s16x8*)(Bbase + 8192 + boff[ks]);
    stageB(t + 1, buf ^ 1, 0);
    __builtin_amdgcn_s_barrier();
    asm volatile("s_waitcnt lgkmcnt(0)" ::: "memory");
    __builtin_amdgcn_s_setprio(1);
#pragma unroll
    for (int mi = 0; mi < 2; ++mi)
#pragma unroll
      for (int ks = 0; ks < 4; ++ks)
        acc[mi][1] = __builtin_amdgcn_mfma_f32_32x32x16_bf16(a[mi][ks], b[ks], acc[mi][1], 0, 0, 0);
    __builtin_amdgcn_s_setprio(0);
    __builtin_amdgcn_s_barrier();

    // ===== p2: quadrant (qm=1, qn=1) — reuse b; 8 A reads =====
#pragma unroll
    for (int mi = 0; mi < 2; ++mi)
#pragma unroll
      for (int ks = 0; ks < 4; ++ks)
        a[mi][ks] = *(const s16x8*)(Abase + 8192 + mi * 4096 + aoff[ks]);
    stageA(t + 2, buf, 0);
    asm volatile("s_waitcnt lgkmcnt(4)" ::: "memory");
    __builtin_amdgcn_s_barrier();
    asm volatile("s_waitcnt lgkmcnt(0)" ::: "memory");
    __builtin_amdgcn_s_setprio(1);
#pragma unroll
    for (int mi = 0; mi < 2; ++mi)
#pragma unroll
      for (int ks = 0; ks < 4; ++ks)
        acc[2 + mi][1] = __builtin_amdgcn_mfma_f32_32x32x16_bf16(a[mi][ks], b[ks], acc[2 + mi][1], 0, 0, 0);
    __builtin_amdgcn_s_setprio(0);
    __builtin_amdgcn_s_barrier();

    // ===== p3: quadrant (qm=1, qn=0) — reuse a; 4 B reads; K-tile boundary vmcnt =====
#pragma unroll
    for (int ks = 0; ks < 4; ++ks)
      b[ks] = *(const s16x8*)(Bbase + boff[ks]);
    stageB(t + 2, buf, 1);
    asm volatile("s_waitcnt vmcnt(4)" ::: "memory");   // counted: next tile landed, 4 in flight
    __builtin_amdgcn_s_barrier();
    asm volatile("s_waitcnt lgkmcnt(0)" ::: "memory");
    __builtin_amdgcn_s_setprio(1);
#pragma unroll
    for (int mi = 0; mi < 2; ++mi)
#pragma unroll
      for (int ks = 0; ks < 4; ++ks)
        acc[2 + mi][0] = __builtin_amdgcn_mfma_f32_32x32x16_bf16(a[mi][ks], b[ks], acc[2 + mi][0], 0, 0, 0);
    __builtin_amdgcn_s_setprio(0);
    __builtin_amdgcn_s_barrier();
  }

  asm volatile("s_waitcnt vmcnt(0)" ::: "memory");   // drain clamped tail prefetches

  // ---- epilogue: bias + fast GELU, fp32 store ----
  // C/D mapping: col = col0 + wni*64 + qn*32 + l31; row = (reg&3) + 8*(reg>>2) + 4*hi32
  float bcol[2];
#pragma unroll
  for (int qn = 0; qn < 2; ++qn)
    bcol[qn] = bias[col0 + (wni << 6) + qn * 32 + l31];

#pragma unroll
  for (int mi = 0; mi < 4; ++mi)
#pragma unroll
    for (int qn = 0; qn < 2; ++qn) {
      const int c = col0 + (wni << 6) + qn * 32 + l31;
#pragma unroll
      for (int reg = 0; reg < 16; ++reg) {
        const int r = row0 + wmi * 128 + mi * 32 + (reg & 3) + 8 * (reg >> 2) + 4 * hi32;
        float y = acc[mi][qn][reg] + bcol[qn];
        out[(size_t)r * HIDDEN + c] = fast_gelu(y);
      }
    }
}

extern "C" void kernel_launch(void* const* d_in, const int* in_sizes, int n_in,
                              void* d_out, int out_size, void* d_ws, size_t ws_size,
                              hipStream_t stream) {
  const float* x     = (const float*)d_in[0];
  const float* gamma = (const float*)d_in[1];
  const float* beta  = (const float*)d_in[2];
  const float* W     = (const float*)d_in[3];
  const float* bias  = (const float*)d_in[4];
  float* out = (float*)d_out;

  unsigned short* xn = (unsigned short*)d_ws;
  unsigned short* wb = (unsigned short*)((char*)d_ws + (size_t)TOKENS * HIDDEN * 2);

  hipLaunchKernelGGL(wconv_kernel, dim3(1024), dim3(256), 0, stream, W, wb);
  hipLaunchKernelGGL(ln_kernel, dim3(TOKENS), dim3(256), 0, stream, x, gamma, beta, xn);
  hipLaunchKernelGGL(gemm_kernel, dim3((TOKENS / BM) * (HIDDEN / BN)), dim3(512), 0, stream,
                     xn, wb, bias, out);
}